// Round 1
// baseline (1253.743 us; speedup 1.0000x reference)
//
#include <hip/hip_runtime.h>
#include <hip/hip_bf16.h>
#include <cstdint>

#define NNODES 50000
#define NEDGES 800000
constexpr float SLOPE = 0.2f;

__device__ __forceinline__ float leakyf(float x){ return x > 0.f ? x : SLOPE * x; }
__device__ __forceinline__ float eluf(float x){ return x > 0.f ? x : expm1f(x); }

// ---------------- CSR build (by dst) ----------------
__global__ void hist_kernel(const int* __restrict__ dst, int* __restrict__ deg, int e){
  int i = blockIdx.x * 256 + threadIdx.x;
  if (i < e) atomicAdd(&deg[dst[i]], 1);
}

__global__ __launch_bounds__(1024) void scan_kernel(const int* __restrict__ deg,
    int* __restrict__ row, int* __restrict__ cur, int n, int etot){
  __shared__ int sums[1024];
  int t = threadIdx.x;
  const int C = (n + 1023) / 1024;
  int base = t * C;
  int s = 0;
  for (int j = 0; j < C; ++j){ int i = base + j; if (i < n) s += deg[i]; }
  sums[t] = s; __syncthreads();
  for (int off = 1; off < 1024; off <<= 1){
    int v = (t >= off) ? sums[t - off] : 0;
    __syncthreads();
    sums[t] += v;
    __syncthreads();
  }
  int pre = (t == 0) ? 0 : sums[t - 1];
  for (int j = 0; j < C; ++j){
    int i = base + j;
    if (i < n){ row[i] = pre; cur[i] = pre; pre += deg[i]; }
  }
  if (t == 0) row[n] = etot;
}

__global__ void scatter_kernel(const int* __restrict__ src, const int* __restrict__ dst,
    int* __restrict__ cur, int* __restrict__ ssrc, int e){
  int i = blockIdx.x * 256 + threadIdx.x;
  if (i < e){
    int pos = atomicAdd(&cur[dst[i]], 1);
    ssrc[pos] = src[i];
  }
}

// ---------------- f32 tiled GEMM: C[n_rows x n_cols] = A[n_rows x K] * B[K x n_cols] ----------------
template<int K>
__global__ __launch_bounds__(256) void gemm_kernel(const float* __restrict__ A,
    const float* __restrict__ B, float* __restrict__ C, int n_rows, int n_cols){
  __shared__ float As[64][68];   // padded stride: bank-conflict-safe column reads
  __shared__ float Bs[64][64];
  int tx = threadIdx.x & 15, ty = threadIdx.x >> 4;
  int row0 = blockIdx.x * 64, col0 = blockIdx.y * 64;
  float acc[4][4] = {};
  for (int k0 = 0; k0 < K; k0 += 64){
    for (int v = threadIdx.x; v < 1024; v += 256){
      int r = v >> 4, c = (v & 15) << 2;
      float4 val = make_float4(0.f, 0.f, 0.f, 0.f);
      int gr = row0 + r;
      if (gr < n_rows) val = *reinterpret_cast<const float4*>(&A[(size_t)gr * K + k0 + c]);
      *reinterpret_cast<float4*>(&As[r][c]) = val;
    }
    for (int v = threadIdx.x; v < 1024; v += 256){
      int r = v >> 4, c = (v & 15) << 2;
      *reinterpret_cast<float4*>(&Bs[r][c]) =
        *reinterpret_cast<const float4*>(&B[(size_t)(k0 + r) * n_cols + col0 + c]);
    }
    __syncthreads();
    #pragma unroll 8
    for (int k = 0; k < 64; ++k){
      float a[4], b[4];
      #pragma unroll
      for (int i = 0; i < 4; ++i) a[i] = As[ty * 4 + i][k];
      #pragma unroll
      for (int j = 0; j < 4; ++j) b[j] = Bs[k][tx * 4 + j];
      #pragma unroll
      for (int i = 0; i < 4; ++i)
        #pragma unroll
        for (int j = 0; j < 4; ++j)
          acc[i][j] += a[i] * b[j];
    }
    __syncthreads();
  }
  #pragma unroll
  for (int i = 0; i < 4; ++i){
    int gr = row0 + ty * 4 + i;
    if (gr < n_rows)
      *reinterpret_cast<float4*>(&C[(size_t)gr * n_cols + col0 + tx * 4]) =
        make_float4(acc[i][0], acc[i][1], acc[i][2], acc[i][3]);
  }
}

// ---------------- el/er: per (node, head) dot(feat, al/ar) ----------------
template<int H, int D>
__global__ void elr_kernel(const float* __restrict__ feat, const float* __restrict__ al,
    const float* __restrict__ ar, float* __restrict__ el, float* __restrict__ er){
  int idx = blockIdx.x * 256 + threadIdx.x;
  if (idx >= NNODES * H) return;
  int h = idx % H;
  const float* f = feat + (size_t)idx * D;
  const float* a = al + h * D;
  const float* r = ar + h * D;
  float sl = 0.f, sr = 0.f;
  #pragma unroll
  for (int d = 0; d < D; d += 4){
    float4 fv = *reinterpret_cast<const float4*>(f + d);
    float4 av = *reinterpret_cast<const float4*>(a + d);
    float4 rv = *reinterpret_cast<const float4*>(r + d);
    sl += fv.x * av.x + fv.y * av.y + fv.z * av.z + fv.w * av.w;
    sr += fv.x * rv.x + fv.y * rv.y + fv.z * rv.z + fv.w * rv.w;
  }
  el[idx] = sl; er[idx] = sr;
}

// ---------------- edge softmax + aggregation: one wave per (node, head) ----------------
template<int H, int D, bool ATOM>
__global__ __launch_bounds__(256) void agg_kernel(const float* __restrict__ feat,
    const float* __restrict__ el, const float* __restrict__ er,
    const int* __restrict__ row, const int* __restrict__ ssrc,
    float* __restrict__ outp, float scale){
  int wid = threadIdx.x >> 6, lane = threadIdx.x & 63;
  int task = blockIdx.x * 4 + wid;
  if (task >= NNODES * H) return;
  int n = task / H, h = task % H;
  int beg = row[n], end = row[n + 1];
  float ern = er[task];
  // pass 1: sum of exp(leaky(el[src]+er[dst]))  (max-shift skipped: |e| small)
  float tot = 0.f;
  for (int i = beg + lane; i < end; i += 64){
    int s = ssrc[i];
    tot += expf(leakyf(el[s * H + h] + ern));
  }
  #pragma unroll
  for (int o = 32; o; o >>= 1) tot += __shfl_xor(tot, o, 64);
  float inv = tot > 0.f ? 1.f / tot : 0.f;
  // pass 2: accumulate alpha * feat[src]
  if constexpr (D == 32){
    int half = lane >> 5, d = lane & 31;
    float acc = 0.f;
    for (int i = beg + half; i < end; i += 2){
      int s = ssrc[i];
      float a = expf(leakyf(el[s * H + h] + ern)) * inv;
      acc += a * feat[((size_t)s * H + h) * D + d];
    }
    acc += __shfl_down(acc, 32, 64);
    if (lane < 32) outp[(size_t)task * D + d] = acc;
  } else { // D == 64
    float acc = 0.f;
    for (int i = beg; i < end; ++i){
      int s = ssrc[i];
      float a = expf(leakyf(el[s * H + h] + ern)) * inv;
      acc += a * feat[((size_t)s * H + h) * D + lane];
    }
    if (ATOM) atomicAdd(&outp[(size_t)n * D + lane], acc * scale);
    else      outp[(size_t)task * D + lane] = acc;
  }
}

// ---------------- epilogues ----------------
__global__ void elu0_kernel(const float* __restrict__ rst, float* __restrict__ h1, int n4){
  int i = blockIdx.x * 256 + threadIdx.x;
  if (i < n4){
    float4 v = reinterpret_cast<const float4*>(rst)[i];
    v.x = eluf(v.x); v.y = eluf(v.y); v.z = eluf(v.z); v.w = eluf(v.w);
    reinterpret_cast<float4*>(h1)[i] = v;
  }
}

__global__ void elu1_kernel(const float* __restrict__ rst, const float* __restrict__ h1,
    float* __restrict__ h2, int n4){
  int i = blockIdx.x * 256 + threadIdx.x;
  if (i < n4){
    float4 v = reinterpret_cast<const float4*>(rst)[i];
    float4 r = reinterpret_cast<const float4*>(h1)[i];
    v.x = eluf(v.x + r.x); v.y = eluf(v.y + r.y); v.z = eluf(v.z + r.z); v.w = eluf(v.w + r.w);
    reinterpret_cast<float4*>(h2)[i] = v;
  }
}

__global__ void wresmean_kernel(const float* __restrict__ Wres, float* __restrict__ wm){
  int i = blockIdx.x * 256 + threadIdx.x;
  if (i < 128 * 64){
    int k = i >> 6, c = i & 63;
    float s = 0.f;
    #pragma unroll
    for (int h = 0; h < 6; ++h) s += Wres[k * 384 + h * 64 + c];
    wm[i] = s * (1.f / 6.f);
  }
}

// ---------------- launch ----------------
extern "C" void kernel_launch(void* const* d_in, const int* in_sizes, int n_in,
                              void* d_out, int out_size, void* d_ws, size_t ws_size,
                              hipStream_t stream){
  const int*   src   = (const int*)d_in[0];
  const int*   dst   = (const int*)d_in[1];
  const float* embed = (const float*)d_in[2];
  const float* W0    = (const float*)d_in[3];
  const float* al0   = (const float*)d_in[4];
  const float* ar0   = (const float*)d_in[5];
  const float* W1    = (const float*)d_in[6];
  const float* al1   = (const float*)d_in[7];
  const float* ar1   = (const float*)d_in[8];
  const float* W2    = (const float*)d_in[9];
  const float* al2   = (const float*)d_in[10];
  const float* ar2   = (const float*)d_in[11];
  const float* Wres  = (const float*)d_in[12];
  float* out = (float*)d_out;

  char* p = (char*)d_ws;
  auto alloc = [&](size_t bytes) -> char* {
    char* r = p; p += (bytes + 255) & ~size_t(255); return r;
  };
  float* feat = (float*)alloc((size_t)NNODES * 384 * 4);
  float* rst  = (float*)alloc((size_t)NNODES * 128 * 4);
  float* h1   = (float*)alloc((size_t)NNODES * 128 * 4);
  float* h2   = (float*)alloc((size_t)NNODES * 128 * 4);
  float* el   = (float*)alloc((size_t)NNODES * 6 * 4);
  float* er   = (float*)alloc((size_t)NNODES * 6 * 4);
  float* wm   = (float*)alloc(128 * 64 * 4);
  int* row    = (int*)alloc((NNODES + 1) * 4);
  int* cur    = (int*)alloc(NNODES * 4);
  int* deg    = (int*)alloc(NNODES * 4);
  int* ssrc   = (int*)alloc(NEDGES * 4);

  // CSR by dst (graph shared by all 3 layers)
  hipMemsetAsync(deg, 0, NNODES * 4, stream);
  hist_kernel<<<(NEDGES + 255) / 256, 256, 0, stream>>>(dst, deg, NEDGES);
  scan_kernel<<<1, 1024, 0, stream>>>(deg, row, cur, NNODES, NEDGES);
  scatter_kernel<<<(NEDGES + 255) / 256, 256, 0, stream>>>(src, dst, cur, ssrc, NEDGES);

  const int GX = (NNODES + 63) / 64;        // 782
  // ---- layer 0: embed[N,64] -> feat[N,4,32]
  gemm_kernel<64><<<dim3(GX, 2), 256, 0, stream>>>(embed, W0, feat, NNODES, 128);
  elr_kernel<4, 32><<<(NNODES * 4 + 255) / 256, 256, 0, stream>>>(feat, al0, ar0, el, er);
  agg_kernel<4, 32, false><<<(NNODES * 4 + 3) / 4, 256, 0, stream>>>(feat, el, er, row, ssrc, rst, 1.f);
  elu0_kernel<<<(NNODES * 32 + 255) / 256, 256, 0, stream>>>(rst, h1, NNODES * 32);

  // ---- layer 1: h1[N,128] -> feat[N,4,32], residual = h1
  gemm_kernel<128><<<dim3(GX, 2), 256, 0, stream>>>(h1, W1, feat, NNODES, 128);
  elr_kernel<4, 32><<<(NNODES * 4 + 255) / 256, 256, 0, stream>>>(feat, al1, ar1, el, er);
  agg_kernel<4, 32, false><<<(NNODES * 4 + 3) / 4, 256, 0, stream>>>(feat, el, er, row, ssrc, rst, 1.f);
  elu1_kernel<<<(NNODES * 32 + 255) / 256, 256, 0, stream>>>(rst, h1, h2, NNODES * 32);

  // ---- layer 2: h2[N,128] -> feat[N,6,64]; out = mean_h(agg + h2@Wres)
  wresmean_kernel<<<32, 256, 0, stream>>>(Wres, wm);
  gemm_kernel<128><<<dim3(GX, 1), 256, 0, stream>>>(h2, wm, out, NNODES, 64);   // out = mean_h(res2)
  gemm_kernel<128><<<dim3(GX, 6), 256, 0, stream>>>(h2, W2, feat, NNODES, 384);
  elr_kernel<6, 64><<<(NNODES * 6 + 255) / 256, 256, 0, stream>>>(feat, al2, ar2, el, er);
  agg_kernel<6, 64, true><<<(NNODES * 6 + 3) / 4, 256, 0, stream>>>(feat, el, er, row, ssrc, out, 1.f / 6.f);
}

// Round 2
// 790.510 us; speedup vs baseline: 1.5860x; 1.5860x over previous
//
#include <hip/hip_runtime.h>
#include <hip/hip_bf16.h>
#include <cstdint>

#define NNODES 50000
#define NEDGES 800000
constexpr float SLOPE = 0.2f;

__device__ __forceinline__ float leakyf(float x){ return x > 0.f ? x : SLOPE * x; }
__device__ __forceinline__ float eluf(float x){ return x > 0.f ? x : expm1f(x); }

// ---------------- CSR build (by dst) ----------------
__global__ void hist_kernel(const int* __restrict__ dst, int* __restrict__ deg, int e){
  int i = blockIdx.x * 256 + threadIdx.x;
  if (i < e) atomicAdd(&deg[dst[i]], 1);
}

__global__ __launch_bounds__(1024) void scan_kernel(const int* __restrict__ deg,
    int* __restrict__ row, int* __restrict__ cur, int n, int etot){
  __shared__ int sums[1024];
  int t = threadIdx.x;
  const int C = (n + 1023) / 1024;
  int base = t * C;
  int s = 0;
  for (int j = 0; j < C; ++j){ int i = base + j; if (i < n) s += deg[i]; }
  sums[t] = s; __syncthreads();
  for (int off = 1; off < 1024; off <<= 1){
    int v = (t >= off) ? sums[t - off] : 0;
    __syncthreads();
    sums[t] += v;
    __syncthreads();
  }
  int pre = (t == 0) ? 0 : sums[t - 1];
  for (int j = 0; j < C; ++j){
    int i = base + j;
    if (i < n){ row[i] = pre; cur[i] = pre; pre += deg[i]; }
  }
  if (t == 0) row[n] = etot;
}

__global__ void scatter_kernel(const int* __restrict__ src, const int* __restrict__ dst,
    int* __restrict__ cur, int* __restrict__ ssrc, int* __restrict__ sdst, int e){
  int i = blockIdx.x * 256 + threadIdx.x;
  if (i < e){
    int d = dst[i];
    int pos = atomicAdd(&cur[d], 1);
    ssrc[pos] = src[i];
    sdst[pos] = d;
  }
}

// ---------------- f32 tiled GEMM: C[n_rows x n_cols] = A[n_rows x K] * B[K x n_cols] ----------------
template<int K>
__global__ __launch_bounds__(256) void gemm_kernel(const float* __restrict__ A,
    const float* __restrict__ B, float* __restrict__ C, int n_rows, int n_cols){
  __shared__ float As[64][68];
  __shared__ float Bs[64][64];
  int tx = threadIdx.x & 15, ty = threadIdx.x >> 4;
  int row0 = blockIdx.x * 64, col0 = blockIdx.y * 64;
  float acc[4][4] = {};
  for (int k0 = 0; k0 < K; k0 += 64){
    for (int v = threadIdx.x; v < 1024; v += 256){
      int r = v >> 4, c = (v & 15) << 2;
      float4 val = make_float4(0.f, 0.f, 0.f, 0.f);
      int gr = row0 + r;
      if (gr < n_rows) val = *reinterpret_cast<const float4*>(&A[(size_t)gr * K + k0 + c]);
      *reinterpret_cast<float4*>(&As[r][c]) = val;
    }
    for (int v = threadIdx.x; v < 1024; v += 256){
      int r = v >> 4, c = (v & 15) << 2;
      *reinterpret_cast<float4*>(&Bs[r][c]) =
        *reinterpret_cast<const float4*>(&B[(size_t)(k0 + r) * n_cols + col0 + c]);
    }
    __syncthreads();
    #pragma unroll 8
    for (int k = 0; k < 64; ++k){
      float a[4], b[4];
      #pragma unroll
      for (int i = 0; i < 4; ++i) a[i] = As[ty * 4 + i][k];
      #pragma unroll
      for (int j = 0; j < 4; ++j) b[j] = Bs[k][tx * 4 + j];
      #pragma unroll
      for (int i = 0; i < 4; ++i)
        #pragma unroll
        for (int j = 0; j < 4; ++j)
          acc[i][j] += a[i] * b[j];
    }
    __syncthreads();
  }
  #pragma unroll
  for (int i = 0; i < 4; ++i){
    int gr = row0 + ty * 4 + i;
    if (gr < n_rows)
      *reinterpret_cast<float4*>(&C[(size_t)gr * n_cols + col0 + tx * 4]) =
        make_float4(acc[i][0], acc[i][1], acc[i][2], acc[i][3]);
  }
}

// ---------------- el/er: per (node, head) dot(feat, al/ar) ----------------
template<int H, int D>
__global__ void elr_kernel(const float* __restrict__ feat, const float* __restrict__ al,
    const float* __restrict__ ar, float* __restrict__ el, float* __restrict__ er){
  int idx = blockIdx.x * 256 + threadIdx.x;
  if (idx >= NNODES * H) return;
  int h = idx % H;
  const float* f = feat + (size_t)idx * D;
  const float* a = al + h * D;
  const float* r = ar + h * D;
  float sl = 0.f, sr = 0.f;
  #pragma unroll
  for (int d = 0; d < D; d += 4){
    float4 fv = *reinterpret_cast<const float4*>(f + d);
    float4 av = *reinterpret_cast<const float4*>(a + d);
    float4 rv = *reinterpret_cast<const float4*>(r + d);
    sl += fv.x * av.x + fv.y * av.y + fv.z * av.z + fv.w * av.w;
    sr += fv.x * rv.x + fv.y * rv.y + fv.z * rv.z + fv.w * rv.w;
  }
  el[idx] = sl; er[idx] = sr;
}

// ---------------- per-(CSR-pos, head) un-normalized attention: ex = exp(leaky(el+er)) ----------------
template<int H>
__global__ void ex_kernel(const float* __restrict__ el, const float* __restrict__ er,
    const int* __restrict__ ssrc, const int* __restrict__ sdst, float* __restrict__ ex, int e){
  int i = blockIdx.x * 256 + threadIdx.x;
  if (i >= e) return;
  int s = ssrc[i], d = sdst[i];
  if constexpr (H == 4){
    float4 a = *reinterpret_cast<const float4*>(&el[s * 4]);
    float4 b = *reinterpret_cast<const float4*>(&er[d * 4]);
    float4 o;
    o.x = expf(leakyf(a.x + b.x));
    o.y = expf(leakyf(a.y + b.y));
    o.z = expf(leakyf(a.z + b.z));
    o.w = expf(leakyf(a.w + b.w));
    *reinterpret_cast<float4*>(&ex[(size_t)i * 4]) = o;
  } else { // H == 6
    const float* ap = &el[s * 6];
    const float* bp = &er[d * 6];
    float2 a0 = *reinterpret_cast<const float2*>(ap);
    float2 a1 = *reinterpret_cast<const float2*>(ap + 2);
    float2 a2 = *reinterpret_cast<const float2*>(ap + 4);
    float2 b0 = *reinterpret_cast<const float2*>(bp);
    float2 b1 = *reinterpret_cast<const float2*>(bp + 2);
    float2 b2 = *reinterpret_cast<const float2*>(bp + 4);
    float2 o0, o1, o2;
    o0.x = expf(leakyf(a0.x + b0.x)); o0.y = expf(leakyf(a0.y + b0.y));
    o1.x = expf(leakyf(a1.x + b1.x)); o1.y = expf(leakyf(a1.y + b1.y));
    o2.x = expf(leakyf(a2.x + b2.x)); o2.y = expf(leakyf(a2.y + b2.y));
    float* op = &ex[(size_t)i * 6];
    *reinterpret_cast<float2*>(op)     = o0;
    *reinterpret_cast<float2*>(op + 2) = o1;
    *reinterpret_cast<float2*>(op + 4) = o2;
  }
}

// ---------------- aggregation: ONE WAVE PER NODE, all heads ----------------
// H=4, D=32: lane covers 2 heads per acc slot (channel = hh*64 + lane).
template<bool RES>
__global__ __launch_bounds__(256) void agg32_kernel(const float* __restrict__ feat,
    const float* __restrict__ ex, const int* __restrict__ row, const int* __restrict__ ssrc,
    const float* __restrict__ resid, float* __restrict__ hout){
  int n = blockIdx.x * 4 + (threadIdx.x >> 6);
  if (n >= NNODES) return;
  int lane = threadIdx.x & 63, half = lane >> 5;
  int beg = row[n], end = row[n + 1];
  // pass 1: per-head denominators (coalesced float4 reads of ex)
  float t0 = 0.f, t1 = 0.f, t2 = 0.f, t3 = 0.f;
  for (int i = beg + lane; i < end; i += 64){
    float4 e = *reinterpret_cast<const float4*>(&ex[(size_t)i * 4]);
    t0 += e.x; t1 += e.y; t2 += e.z; t3 += e.w;
  }
  #pragma unroll
  for (int o = 32; o; o >>= 1){
    t0 += __shfl_xor(t0, o, 64); t1 += __shfl_xor(t1, o, 64);
    t2 += __shfl_xor(t2, o, 64); t3 += __shfl_xor(t3, o, 64);
  }
  float invA = half ? (t1 > 0.f ? 1.f / t1 : 0.f) : (t0 > 0.f ? 1.f / t0 : 0.f);
  float invB = half ? (t3 > 0.f ? 1.f / t3 : 0.f) : (t2 > 0.f ? 1.f / t2 : 0.f);
  // pass 2: two independent 256B gathers per edge
  float acc0 = 0.f, acc1 = 0.f;
  for (int i = beg; i < end; ++i){
    int s = ssrc[i];
    const float* fr = feat + (size_t)s * 128;
    float eA = ex[(size_t)i * 4 + half];
    float eB = ex[(size_t)i * 4 + 2 + half];
    acc0 += eA * fr[lane];
    acc1 += eB * fr[64 + lane];
  }
  float v0 = acc0 * invA, v1 = acc1 * invB;
  size_t o0 = (size_t)n * 128 + lane;
  if constexpr (RES){ v0 += resid[o0]; v1 += resid[o0 + 64]; }
  hout[o0]      = eluf(v0);
  hout[o0 + 64] = eluf(v1);
}

// H=6, D=64: lane = channel; acc[6]; out = res(preloaded in out) + mean over heads.
__global__ __launch_bounds__(256) void agg64_kernel(const float* __restrict__ feat,
    const float* __restrict__ ex, const int* __restrict__ row, const int* __restrict__ ssrc,
    float* __restrict__ outp){
  int n = blockIdx.x * 4 + (threadIdx.x >> 6);
  if (n >= NNODES) return;
  int lane = threadIdx.x & 63;
  int beg = row[n], end = row[n + 1];
  float t[6] = {};
  for (int i = beg + lane; i < end; i += 64){
    const float* e = &ex[(size_t)i * 6];
    float2 a = *reinterpret_cast<const float2*>(e);
    float2 b = *reinterpret_cast<const float2*>(e + 2);
    float2 c = *reinterpret_cast<const float2*>(e + 4);
    t[0] += a.x; t[1] += a.y; t[2] += b.x; t[3] += b.y; t[4] += c.x; t[5] += c.y;
  }
  #pragma unroll
  for (int o = 32; o; o >>= 1){
    #pragma unroll
    for (int h = 0; h < 6; ++h) t[h] += __shfl_xor(t[h], o, 64);
  }
  float inv[6];
  #pragma unroll
  for (int h = 0; h < 6; ++h) inv[h] = t[h] > 0.f ? 1.f / t[h] : 0.f;
  float acc[6] = {};
  for (int i = beg; i < end; ++i){
    int s = ssrc[i];
    const float* fr = feat + (size_t)s * 384;
    const float* e = &ex[(size_t)i * 6];
    float2 a = *reinterpret_cast<const float2*>(e);
    float2 b = *reinterpret_cast<const float2*>(e + 2);
    float2 c = *reinterpret_cast<const float2*>(e + 4);
    acc[0] += a.x * fr[lane];       acc[1] += a.y * fr[64 + lane];
    acc[2] += b.x * fr[128 + lane]; acc[3] += b.y * fr[192 + lane];
    acc[4] += c.x * fr[256 + lane]; acc[5] += c.y * fr[320 + lane];
  }
  float s6 = 0.f;
  #pragma unroll
  for (int h = 0; h < 6; ++h) s6 += acc[h] * inv[h];
  size_t o = (size_t)n * 64 + lane;
  outp[o] = outp[o] + s6 * (1.f / 6.f);
}

// ---------------- Wres mean fold ----------------
__global__ void wresmean_kernel(const float* __restrict__ Wres, float* __restrict__ wm){
  int i = blockIdx.x * 256 + threadIdx.x;
  if (i < 128 * 64){
    int k = i >> 6, c = i & 63;
    float s = 0.f;
    #pragma unroll
    for (int h = 0; h < 6; ++h) s += Wres[k * 384 + h * 64 + c];
    wm[i] = s * (1.f / 6.f);
  }
}

// ---------------- launch ----------------
extern "C" void kernel_launch(void* const* d_in, const int* in_sizes, int n_in,
                              void* d_out, int out_size, void* d_ws, size_t ws_size,
                              hipStream_t stream){
  const int*   src   = (const int*)d_in[0];
  const int*   dst   = (const int*)d_in[1];
  const float* embed = (const float*)d_in[2];
  const float* W0    = (const float*)d_in[3];
  const float* al0   = (const float*)d_in[4];
  const float* ar0   = (const float*)d_in[5];
  const float* W1    = (const float*)d_in[6];
  const float* al1   = (const float*)d_in[7];
  const float* ar1   = (const float*)d_in[8];
  const float* W2    = (const float*)d_in[9];
  const float* al2   = (const float*)d_in[10];
  const float* ar2   = (const float*)d_in[11];
  const float* Wres  = (const float*)d_in[12];
  float* out = (float*)d_out;

  char* p = (char*)d_ws;
  auto alloc = [&](size_t bytes) -> char* {
    char* r = p; p += (bytes + 255) & ~size_t(255); return r;
  };
  float* feat = (float*)alloc((size_t)NNODES * 384 * 4);
  float* h1   = (float*)alloc((size_t)NNODES * 128 * 4);
  float* h2   = (float*)alloc((size_t)NNODES * 128 * 4);
  float* el   = (float*)alloc((size_t)NNODES * 6 * 4);
  float* er   = (float*)alloc((size_t)NNODES * 6 * 4);
  float* ex   = (float*)alloc((size_t)NEDGES * 6 * 4);
  float* wm   = (float*)alloc(128 * 64 * 4);
  int* row    = (int*)alloc((NNODES + 1) * 4);
  int* cur    = (int*)alloc(NNODES * 4);
  int* deg    = (int*)alloc(NNODES * 4);
  int* ssrc   = (int*)alloc(NEDGES * 4);
  int* sdst   = (int*)alloc(NEDGES * 4);

  // CSR by dst (graph shared by all 3 layers)
  hipMemsetAsync(deg, 0, NNODES * 4, stream);
  hist_kernel<<<(NEDGES + 255) / 256, 256, 0, stream>>>(dst, deg, NEDGES);
  scan_kernel<<<1, 1024, 0, stream>>>(deg, row, cur, NNODES, NEDGES);
  scatter_kernel<<<(NEDGES + 255) / 256, 256, 0, stream>>>(src, dst, cur, ssrc, sdst, NEDGES);

  const int GX = (NNODES + 63) / 64;        // 782
  const int GE = (NEDGES + 255) / 256;
  const int GN = (NNODES + 3) / 4;

  // ---- layer 0: embed[N,64] -> feat[N,4,32]
  gemm_kernel<64><<<dim3(GX, 2), 256, 0, stream>>>(embed, W0, feat, NNODES, 128);
  elr_kernel<4, 32><<<(NNODES * 4 + 255) / 256, 256, 0, stream>>>(feat, al0, ar0, el, er);
  ex_kernel<4><<<GE, 256, 0, stream>>>(el, er, ssrc, sdst, ex, NEDGES);
  agg32_kernel<false><<<GN, 256, 0, stream>>>(feat, ex, row, ssrc, nullptr, h1);

  // ---- layer 1: h1[N,128] -> feat[N,4,32], residual = h1
  gemm_kernel<128><<<dim3(GX, 2), 256, 0, stream>>>(h1, W1, feat, NNODES, 128);
  elr_kernel<4, 32><<<(NNODES * 4 + 255) / 256, 256, 0, stream>>>(feat, al1, ar1, el, er);
  ex_kernel<4><<<GE, 256, 0, stream>>>(el, er, ssrc, sdst, ex, NEDGES);
  agg32_kernel<true><<<GN, 256, 0, stream>>>(feat, ex, row, ssrc, h1, h2);

  // ---- layer 2: h2[N,128] -> feat[N,6,64]; out = mean_h(agg + h2@Wres)
  wresmean_kernel<<<32, 256, 0, stream>>>(Wres, wm);
  gemm_kernel<128><<<dim3(GX, 1), 256, 0, stream>>>(h2, wm, out, NNODES, 64);   // out = mean_h(res2)
  gemm_kernel<128><<<dim3(GX, 6), 256, 0, stream>>>(h2, W2, feat, NNODES, 384);
  elr_kernel<6, 64><<<(NNODES * 6 + 255) / 256, 256, 0, stream>>>(feat, al2, ar2, el, er);
  ex_kernel<6><<<GE, 256, 0, stream>>>(el, er, ssrc, sdst, ex, NEDGES);
  agg64_kernel<<<GN, 256, 0, stream>>>(feat, ex, row, ssrc, out);
}